// Round 5
// baseline (1284.147 us; speedup 1.0000x reference)
//
#include <hip/hip_runtime.h>
#include <hip/hip_bf16.h>

typedef __attribute__((ext_vector_type(4))) int int4v;

#define MFMA_I8(a, b, c) __builtin_amdgcn_mfma_i32_16x16x64_i8((a), (b), (c), 0, 0, 0)
#define GLDS16(g, l)                                                                        \
  __builtin_amdgcn_global_load_lds((const __attribute__((address_space(1))) void*)(g),      \
                                   (__attribute__((address_space(3))) void*)(l), 16, 0, 0)
#define SBAR() __builtin_amdgcn_s_barrier()
#define SCHED0() __builtin_amdgcn_sched_barrier(0)

static constexpr int NTOK = 4096;
static constexpr int DDIM = 4096;
static constexpr int FDIM = 11008;

// ---------------------------------------------------------------- utilities

__device__ __forceinline__ float wave_max64(float m) {
#pragma unroll
  for (int o = 32; o > 0; o >>= 1) m = fmaxf(m, __shfl_xor(m, o));
  return m;
}

__global__ void zero_slots(unsigned* s) {
  if (threadIdx.x < 16) s[threadIdx.x] = 0u;
}

__global__ void absmax_kernel(const float* __restrict__ p, int n4, unsigned* __restrict__ slot) {
  float m = 0.f;
  const int stride = gridDim.x * blockDim.x;
  for (int i = blockIdx.x * blockDim.x + threadIdx.x; i < n4; i += stride) {
    float4 v = reinterpret_cast<const float4*>(p)[i];
    m = fmaxf(fmaxf(fabsf(v.x), fabsf(v.y)), fmaxf(fmaxf(fabsf(v.z), fabsf(v.w)), m));
  }
  m = wave_max64(m);
  __shared__ float wm[4];
  const int lane = threadIdx.x & 63, w = threadIdx.x >> 6;
  if (lane == 0) wm[w] = m;
  __syncthreads();
  if (threadIdx.x == 0) {
    m = fmaxf(fmaxf(wm[0], wm[1]), fmaxf(wm[2], wm[3]));
    atomicMax(slot, __float_as_uint(m));
  }
}

// q = rint(t / s) as signed i8, 4 packed per u32 (|q| <= 127, exact)
__global__ void quant_kernel(const float* __restrict__ in, unsigned* __restrict__ out,
                             int n4, const unsigned* __restrict__ slot) {
  const float s = fmaxf(__uint_as_float(*slot), 1e-8f) / 127.0f;
  const int stride = gridDim.x * blockDim.x;
  for (int i = blockIdx.x * blockDim.x + threadIdx.x; i < n4; i += stride) {
    float4 v = reinterpret_cast<const float4*>(in)[i];
    const int q0 = (int)rintf(v.x / s), q1 = (int)rintf(v.y / s);
    const int q2 = (int)rintf(v.z / s), q3 = (int)rintf(v.w / s);
    out[i] = (unsigned)(q0 & 255) | ((unsigned)(q1 & 255) << 8) |
             ((unsigned)(q2 & 255) << 16) | ((unsigned)(q3 & 255) << 24);
  }
}

// --------------------------------------------- 128x128 occupancy-first GEMM
// C[M][N] = scale * A[M][K] . B[N][K]^T, int8, mfma_i32_16x16x64_i8 (exact).
// 256 threads = 4 waves (2M x 2N), per-wave C = 64x64 (acc = 16 int4v = 64r).
// BK=64 (64 B/row). LDS 40 KB/block: A dbuf 2x8KB @0, B triple-buf 3x8KB
// @16384 -> 3 blocks/CU (12 waves) via __launch_bounds__(256,3).
// Swizzle (64B rows, 4 granules of 16B): g_phys = g ^ ((row>>1)&3), applied
// on global SOURCE (linear LDS dest) and on ds_read (both-sides rule).
// Schedule: per tile, boundary {vmcnt(2); barrier}; then stage A(t+1)->A^1,
// B(t+2)->B[(t+2)%3] (reader-disjoint, no intra-tile barriers); frag reads;
// 16 MFMA. Queue at boundary T: B(T)2,A(T)2,B(T+1)2 -> vmcnt(2) drains
// exactly A(T),B(T). Cross-block overlap hides residual stalls.
// MODE 0: C=silu(v)  MODE 1: C=v*SG (in-place) + absmax->hslot  MODE 2: C=v
template <int MODE>
__global__ __launch_bounds__(256, 3) void gemm_i8(
    const signed char* __restrict__ Aq, const signed char* __restrict__ Bq,
    float* C, const float* SG, const unsigned* __restrict__ slots, int sA, int sB,
    unsigned* hslot, int K, int ldc) {
  __shared__ char lds[40960];

  const int t = threadIdx.x;
  const int l = t & 63;
  const int w = t >> 6;   // wave 0..3
  const int wm = w >> 1;  // 0..1
  const int wn = w & 1;   // 0..1

  // XCD-aware column-major chunking (nwg % 8 == 0 for all our grids)
  const int gx = gridDim.x, gy = gridDim.y;
  const int nwg = gx * gy;
  const int i0 = blockIdx.y * gx + blockIdx.x;
  const int cid = (i0 & 7) * (nwg >> 3) + (i0 >> 3);
  const int rowA0 = (cid % gy) << 7;  // C-row tile base
  const int colB0 = (cid / gy) << 7;  // C-col (B-row) base

  // staging source (per-thread): one GLDS covers 64 rows x 64 B
  const int rl = t >> 2;                      // row 0..63
  const int gl = (t & 3) ^ ((rl >> 1) & 3);   // pre-swizzled granule
  const signed char* aP = Aq + (size_t)(rowA0 + rl) * K + gl * 16;
  const signed char* bP = Bq + (size_t)(colB0 + rl) * K + gl * 16;
  const size_t rstep = (size_t)64 * K;  // +64 rows
  const int stW = w * 1024;             // wave-uniform LDS byte base

// swizzled LDS frag read (BUF = region byte offset, ROW 0..127)
#define LDSF(BUF, ROW)                                                                   \
  (*reinterpret_cast<const int4v*>(                                                      \
      &lds[(BUF) + (ROW) * 64 + ((((l >> 4) ^ (((ROW) >> 1) & 3))) << 4)]))

  int4v acc[4][4];
#pragma unroll
  for (int m = 0; m < 4; ++m)
#pragma unroll
    for (int n = 0; n < 4; ++n) acc[m][n] = (int4v){0, 0, 0, 0};

  const int NT = K >> 6;
  const int arow = wm * 64 + (l & 15);
  const int brow = wn * 64 + (l & 15);

  // prologue: A(0)->buf0, B(0)->16384, B(1)->24576
  GLDS16(aP, &lds[0 + stW]);
  GLDS16(aP + rstep, &lds[4096 + stW]);
  GLDS16(bP, &lds[16384 + stW]);
  GLDS16(bP + rstep, &lds[16384 + 4096 + stW]);
  GLDS16(bP + 64, &lds[24576 + stW]);
  GLDS16(bP + rstep + 64, &lds[24576 + 4096 + stW]);

  int aR = 0;      // A read buf (0 / 8192)
  int bR = 16384;  // B read buf
  int bW = 32768;  // B write buf (tile kt+2)

  for (int kt = 0; kt < NT; ++kt) {
    // ---- tile boundary
    SCHED0();
    if (kt + 1 < NT) {
      asm volatile("s_waitcnt vmcnt(2)" ::: "memory");
    } else {
      asm volatile("s_waitcnt vmcnt(0)" ::: "memory");
    }
    SBAR();
    SCHED0();

    // ---- stage next tiles (regions disjoint from any current reader)
    const int aW = aR ^ 8192;
    if (kt + 1 < NT) {
      const signed char* p = aP + (size_t)(kt + 1) * 64;
      GLDS16(p, &lds[aW + stW]);
      GLDS16(p + rstep, &lds[aW + 4096 + stW]);
    }
    if (kt + 2 < NT) {
      const signed char* p = bP + (size_t)(kt + 2) * 64;
      GLDS16(p, &lds[bW + stW]);
      GLDS16(p + rstep, &lds[bW + 4096 + stW]);
    }
    SCHED0();

    // ---- frag reads + MFMA
    int4v a[4], b[4];
#pragma unroll
    for (int m = 0; m < 4; ++m) a[m] = LDSF(aR, arow + m * 16);
#pragma unroll
    for (int n = 0; n < 4; ++n) b[n] = LDSF(bR, brow + n * 16);
    __builtin_amdgcn_s_setprio(1);
#pragma unroll
    for (int m = 0; m < 4; ++m)
#pragma unroll
      for (int n = 0; n < 4; ++n) acc[m][n] = MFMA_I8(a[m], b[n], acc[m][n]);
    __builtin_amdgcn_s_setprio(0);

    // ---- rotate buffers
    aR = aW;
    bR = (bR == 32768) ? 16384 : bR + 8192;
    bW = (bW == 32768) ? 16384 : bW + 8192;
  }

  // ------------------------------------------------------------- epilogue
  const float sa = fmaxf(__uint_as_float(slots[sA]), 1e-8f) / 127.0f;
  const float sb = fmaxf(__uint_as_float(slots[sB]), 1e-8f) / 127.0f;
  const float s = sa * sb;
  const int crow0 = rowA0 + wm * 64 + ((l >> 4) << 2);
  const int ccol0 = colB0 + wn * 64 + (l & 15);
  float hmax = 0.f;
#pragma unroll
  for (int m = 0; m < 4; ++m)
#pragma unroll
    for (int n = 0; n < 4; ++n)
#pragma unroll
      for (int j = 0; j < 4; ++j) {
        const int row = crow0 + m * 16 + j;
        const int col = ccol0 + n * 16;
        const float v = (float)acc[m][n][j] * s;
        if constexpr (MODE == 0) {
          C[(size_t)row * ldc + col] = v / (1.f + expf(-v));  // silu
        } else if constexpr (MODE == 1) {
          const float h = v * SG[(size_t)row * ldc + col];
          C[(size_t)row * ldc + col] = h;
          hmax = fmaxf(hmax, fabsf(h));
        } else {
          C[(size_t)row * ldc + col] = v;
        }
      }
  if constexpr (MODE == 1) {
    hmax = wave_max64(hmax);
    if (l == 0) atomicMax(hslot, __float_as_uint(hmax));
  }
#undef LDSF
}

// ------------------------------------------------------------------- launch

extern "C" void kernel_launch(void* const* d_in, const int* in_sizes, int n_in,
                              void* d_out, int out_size, void* d_ws, size_t ws_size,
                              hipStream_t stream) {
  const float* x = (const float*)d_in[0];
  const float* w1 = (const float*)d_in[1];
  const float* w3 = (const float*)d_in[2];
  const float* w2 = (const float*)d_in[3];
  float* out = (float*)d_out;
  char* ws = (char*)d_ws;

  unsigned* slots = (unsigned*)ws;  // [0]=x [1]=w1 [2]=w3 [3]=w2 [4]=h absmax
  size_t off = 256;
  signed char* qx = (signed char*)(ws + off);
  off += (size_t)NTOK * DDIM;
  signed char* qw3 = (signed char*)(ws + off);
  off += (size_t)FDIM * DDIM;
  signed char* qw1 = (signed char*)(ws + off);
  off += (size_t)FDIM * DDIM;
  signed char* qw2 = (signed char*)(ws + off);
  off += (size_t)FDIM * DDIM;
  float* SGH = (float*)(ws + off);  // silu(gate), overwritten in-place by h
  off += (size_t)NTOK * FDIM * 4;
  signed char* qh = (signed char*)(ws + off);
  off += (size_t)NTOK * FDIM;  // ~385 MB total

  const int n4x = NTOK * DDIM / 4;
  const int n4w = FDIM * DDIM / 4;
  const int n4h = NTOK * FDIM / 4;

  zero_slots<<<1, 64, 0, stream>>>(slots);
  absmax_kernel<<<2048, 256, 0, stream>>>(x, n4x, slots + 0);
  absmax_kernel<<<2048, 256, 0, stream>>>(w1, n4w, slots + 1);
  absmax_kernel<<<2048, 256, 0, stream>>>(w3, n4w, slots + 2);
  absmax_kernel<<<2048, 256, 0, stream>>>(w2, n4w, slots + 3);

  quant_kernel<<<2048, 256, 0, stream>>>(x, (unsigned*)qx, n4x, slots + 0);
  quant_kernel<<<2048, 256, 0, stream>>>(w1, (unsigned*)qw1, n4w, slots + 1);
  quant_kernel<<<2048, 256, 0, stream>>>(w3, (unsigned*)qw3, n4w, slots + 2);
  quant_kernel<<<2048, 256, 0, stream>>>(w2, (unsigned*)qw2, n4w, slots + 3);

  const dim3 gUp(FDIM / 128, NTOK / 128);  // 86 x 32 = 2752 wgs (%8==0)
  const dim3 gDn(DDIM / 128, NTOK / 128);  // 32 x 32 = 1024 wgs (%8==0)
  // gate: SG = silu(x.w3^T * s)
  gemm_i8<0><<<gUp, 256, 0, stream>>>(qx, qw3, SGH, nullptr, slots, 0, 2, nullptr, DDIM, FDIM);
  // up: H = (x.w1^T * s) * SG, in-place over SGH, + absmax(H)
  gemm_i8<1><<<gUp, 256, 0, stream>>>(qx, qw1, SGH, SGH, slots, 0, 1, slots + 4, DDIM, FDIM);
  quant_kernel<<<2048, 256, 0, stream>>>(SGH, (unsigned*)qh, n4h, slots + 4);
  // down: out = (h.w2^T) * s
  gemm_i8<2><<<gDn, 256, 0, stream>>>(qh, qw2, out, nullptr, slots, 4, 3, nullptr, FDIM, DDIM);
}

// Round 6
// 1043.235 us; speedup vs baseline: 1.2309x; 1.2309x over previous
//
#include <hip/hip_runtime.h>
#include <hip/hip_bf16.h>

typedef __attribute__((ext_vector_type(4))) int int4v;

#define MFMA_I8(a, b, c) __builtin_amdgcn_mfma_i32_16x16x64_i8((a), (b), (c), 0, 0, 0)
#define GLDS16(g, l)                                                                        \
  __builtin_amdgcn_global_load_lds((const __attribute__((address_space(1))) void*)(g),      \
                                   (__attribute__((address_space(3))) void*)(l), 16, 0, 0)
#define SBAR() __builtin_amdgcn_s_barrier()
#define SCHED0() __builtin_amdgcn_sched_barrier(0)

static constexpr int NTOK = 4096;
static constexpr int DDIM = 4096;
static constexpr int FDIM = 11008;

// ---------------------------------------------------------------- utilities

__device__ __forceinline__ float wave_max64(float m) {
#pragma unroll
  for (int o = 32; o > 0; o >>= 1) m = fmaxf(m, __shfl_xor(m, o));
  return m;
}

__global__ void zero_slots(unsigned* s) {
  if (threadIdx.x < 16) s[threadIdx.x] = 0u;
}

__global__ void absmax_kernel(const float* __restrict__ p, int n4, unsigned* __restrict__ slot) {
  float m = 0.f;
  const int stride = gridDim.x * blockDim.x;
  for (int i = blockIdx.x * blockDim.x + threadIdx.x; i < n4; i += stride) {
    float4 v = reinterpret_cast<const float4*>(p)[i];
    m = fmaxf(fmaxf(fabsf(v.x), fabsf(v.y)), fmaxf(fmaxf(fabsf(v.z), fabsf(v.w)), m));
  }
  m = wave_max64(m);
  __shared__ float wm[4];
  const int lane = threadIdx.x & 63, w = threadIdx.x >> 6;
  if (lane == 0) wm[w] = m;
  __syncthreads();
  if (threadIdx.x == 0) {
    m = fmaxf(fmaxf(wm[0], wm[1]), fmaxf(wm[2], wm[3]));
    atomicMax(slot, __float_as_uint(m));
  }
}

// q = rint(t / s) as signed i8, 4 packed per u32 (|q| <= 127, exact)
__global__ void quant_kernel(const float* __restrict__ in, unsigned* __restrict__ out,
                             int n4, const unsigned* __restrict__ slot) {
  const float s = fmaxf(__uint_as_float(*slot), 1e-8f) / 127.0f;
  const int stride = gridDim.x * blockDim.x;
  for (int i = blockIdx.x * blockDim.x + threadIdx.x; i < n4; i += stride) {
    float4 v = reinterpret_cast<const float4*>(in)[i];
    const int q0 = (int)rintf(v.x / s), q1 = (int)rintf(v.y / s);
    const int q2 = (int)rintf(v.z / s), q3 = (int)rintf(v.w / s);
    out[i] = (unsigned)(q0 & 255) | ((unsigned)(q1 & 255) << 8) |
             ((unsigned)(q2 & 255) << 16) | ((unsigned)(q3 & 255) << 24);
  }
}

// ------------------------------------------- fused gate+up GLU GEMM (i8)
// H[M][F] = (A.B1^T * s1) * silu(A.B3^T * s3); A=qx[M][K], B3/B1=[F][K] i8.
// Tile 128x256, 8 waves (2M x 4N), per-wave 64x64 PER OUTPUT (acc3+acc1 =
// 128 VGPR). BK=64 i8 (one 16x16x64 K-depth). LDS 80 KB: per buf (40960 B):
// A[128][64] @0, B3[256][64] @8192, B1[256][64] @24576; double-buffered.
// Swizzle: 16B granule g_phys = g ^ ((row>>1)&3) on global source (linear
// LDS dest) + same XOR on ds_read (both-sides rule); 2-way max = free.
// Schedule per tile kt (buf b=kt&1): boundary {vmcnt(3); barrier};
//   ph1: ds_read A(4)+B3(4) frags; stage B1(kt+1)->buf[kt+1&1]; bar;
//        16 MFMA gate; bar;
//   ph2: ds_read B1(4) frags (A frags reused from regs);
//        stage A(kt+2),B3(kt+2)->buf b (regions free after ph1); bar;
//        16 MFMA up;   (next boundary closes)
// Queue at boundary: [B1(kt)x2, A(kt+1), B3(kt+1)x2] -> vmcnt(3) drains
// B1(kt) and everything older; A/B3(kt+1) keep ~4 phases of cover.
__global__ __launch_bounds__(512, 2) void gemm_glu(
    const signed char* __restrict__ Aq, const signed char* __restrict__ B3q,
    const signed char* __restrict__ B1q, float* __restrict__ H,
    const unsigned* __restrict__ slots, unsigned* __restrict__ hslot) {
  constexpr int K = DDIM;
  __shared__ char lds[81920];

  const int t = threadIdx.x;
  const int l = t & 63;
  const int w = t >> 6;   // wave 0..7
  const int wm = w >> 2;  // 0..1 (M)
  const int wn = w & 3;   // 0..3 (N)

  // XCD-aware column-major chunking (nwg = 43*32 = 1376, %8==0)
  const int gx = gridDim.x, gy = gridDim.y;
  const int nwg = gx * gy;
  const int i0 = blockIdx.y * gx + blockIdx.x;
  const int cid = (i0 & 7) * (nwg >> 3) + (i0 >> 3);
  const int rowA0 = (cid % gy) << 7;  // 128-row tile
  const int colB0 = (cid / gy) << 8;  // 256-col tile

  // staging sources: thread t covers local row t>>2, pre-swizzled granule
  const int rl = t >> 2;                  // 0..127
  const int gl = (t & 3) ^ ((t >> 3) & 3);
  const signed char* aP = Aq + (size_t)(rowA0 + rl) * K + gl * 16;
  const signed char* b3P = B3q + (size_t)(colB0 + rl) * K + gl * 16;
  const signed char* b1P = B1q + (size_t)(colB0 + rl) * K + gl * 16;
  const size_t rstep = (size_t)128 * K;  // +128 rows
  const int stW = w * 1024;              // wave-uniform LDS slice

#define STA(KO, B) GLDS16(aP + (KO), &lds[(B)*40960 + stW])
#define STB3(KO, B)                                               \
  do {                                                            \
    GLDS16(b3P + (KO), &lds[(B)*40960 + 8192 + stW]);             \
    GLDS16(b3P + rstep + (KO), &lds[(B)*40960 + 16384 + stW]);    \
  } while (0)
#define STB1(KO, B)                                               \
  do {                                                            \
    GLDS16(b1P + (KO), &lds[(B)*40960 + 24576 + stW]);            \
    GLDS16(b1P + rstep + (KO), &lds[(B)*40960 + 32768 + stW]);    \
  } while (0)

// swizzled LDS frag read (BASE = region byte base, ROW local)
#define LDSF(BASE, ROW)                                                       \
  (*reinterpret_cast<const int4v*>(                                           \
      &lds[(BASE) + (ROW)*64 + (((l >> 4) ^ (((ROW) >> 1) & 3)) << 4)]))

  int4v acc3[4][4], acc1[4][4];
#pragma unroll
  for (int m = 0; m < 4; ++m)
#pragma unroll
    for (int n = 0; n < 4; ++n) {
      acc3[m][n] = (int4v){0, 0, 0, 0};
      acc1[m][n] = (int4v){0, 0, 0, 0};
    }

  const int NT = K >> 6;               // 64 tiles of K=64
  const int arow = wm * 64 + (l & 15);
  const int brow = wn * 64 + (l & 15);

  // prologue: tile0 full -> buf0; tile1 A,B3 -> buf1
  STA(0, 0);
  STB3(0, 0);
  STB1(0, 0);
  STA(64, 1);
  STB3(64, 1);

  for (int kt = 0; kt < NT; ++kt) {
    const int b = kt & 1;
    const int base = b * 40960;

    // ---- boundary
    SCHED0();
    if (kt + 1 < NT) {
      asm volatile("s_waitcnt vmcnt(3)" ::: "memory");
    } else {
      asm volatile("s_waitcnt vmcnt(0)" ::: "memory");
    }
    SBAR();
    SCHED0();

    int4v a[4], bf[4];

    // ---- phase 1: A + B3 frags; stage B1(kt+1)
#pragma unroll
    for (int m = 0; m < 4; ++m) a[m] = LDSF(base, arow + m * 16);
#pragma unroll
    for (int n = 0; n < 4; ++n) bf[n] = LDSF(base + 8192, brow + n * 16);
    if (kt + 1 < NT) STB1((size_t)(kt + 1) * 64, (kt + 1) & 1);
    SCHED0(); SBAR(); SCHED0();
    __builtin_amdgcn_s_setprio(1);
#pragma unroll
    for (int m = 0; m < 4; ++m)
#pragma unroll
      for (int n = 0; n < 4; ++n) acc3[m][n] = MFMA_I8(a[m], bf[n], acc3[m][n]);
    __builtin_amdgcn_s_setprio(0);
    SCHED0(); SBAR(); SCHED0();

    // ---- phase 2: B1 frags (A reused); stage A(kt+2), B3(kt+2) -> buf b
#pragma unroll
    for (int n = 0; n < 4; ++n) bf[n] = LDSF(base + 24576, brow + n * 16);
    if (kt + 2 < NT) {
      STA((size_t)(kt + 2) * 64, b);
      STB3((size_t)(kt + 2) * 64, b);
    }
    SCHED0(); SBAR(); SCHED0();
    __builtin_amdgcn_s_setprio(1);
#pragma unroll
    for (int m = 0; m < 4; ++m)
#pragma unroll
      for (int n = 0; n < 4; ++n) acc1[m][n] = MFMA_I8(a[m], bf[n], acc1[m][n]);
    __builtin_amdgcn_s_setprio(0);
    // next boundary provides the closing barrier
  }

  // ------------------------------------------------------------- epilogue
  const float sx = fmaxf(__uint_as_float(slots[0]), 1e-8f) / 127.0f;
  const float sw1 = fmaxf(__uint_as_float(slots[1]), 1e-8f) / 127.0f;
  const float sw3 = fmaxf(__uint_as_float(slots[2]), 1e-8f) / 127.0f;
  const float s3 = sx * sw3, s1 = sx * sw1;
  const int crow0 = rowA0 + wm * 64 + ((l >> 4) << 2);
  const int ccol0 = colB0 + wn * 64 + (l & 15);
  float hmax = 0.f;
#pragma unroll
  for (int m = 0; m < 4; ++m)
#pragma unroll
    for (int n = 0; n < 4; ++n)
#pragma unroll
      for (int j = 0; j < 4; ++j) {
        const int row = crow0 + m * 16 + j;
        const int col = ccol0 + n * 16;
        const float g = (float)acc3[m][n][j] * s3;
        const float gate = g / (1.f + expf(-g));  // silu
        const float h = (float)acc1[m][n][j] * s1 * gate;
        H[(size_t)row * FDIM + col] = h;
        hmax = fmaxf(hmax, fabsf(h));
      }
  hmax = wave_max64(hmax);
  if (l == 0) atomicMax(hslot, __float_as_uint(hmax));
#undef STA
#undef STB3
#undef STB1
#undef LDSF
}

// ------------------------------------------------ 256x256 8-phase down GEMM
// out[M][N] = s * A[M][K].B[N][K]^T  (round-4 structure, measured best here)
__global__ __launch_bounds__(512, 2) void gemm_down(
    const signed char* __restrict__ Aq, const signed char* __restrict__ Bq,
    float* __restrict__ C, const unsigned* __restrict__ slots, int sA, int sB,
    int K, int ldc) {
  __shared__ char lds[131072];

  const int t = threadIdx.x;
  const int l = t & 63;
  const int w = t >> 6;
  const int wm = w >> 2;
  const int wn = w & 3;

  const int gx = gridDim.x, gy = gridDim.y;
  const int nwg = gx * gy;
  const int i0 = blockIdx.y * gx + blockIdx.x;
  const int cid = (i0 & 7) * (nwg >> 3) + (i0 >> 3);
  const int rowA0 = (cid % gy) << 8;
  const int colB0 = (cid / gy) << 8;

  const int rl = t >> 3;
  const int c16 = (t & 7) ^ (rl & 7);
  const size_t aOff0 = (size_t)(rowA0 + rl) * K + c16 * 16;
  const size_t aOff1 = aOff0 + (size_t)64 * K;
  const size_t bOff0 = (size_t)(colB0 + rl) * K + c16 * 16;
  const size_t bOff1 = bOff0 + (size_t)64 * K;
  const size_t hstep = (size_t)128 * K;
  const int stW = w * 1024;

#define STAGE2(PTR, O0, O1, LB)             \
  do {                                      \
    GLDS16((PTR) + (O0), &lds[(LB) + stW]); \
    GLDS16((PTR) + (O1), &lds[(LB) + 8192 + stW]); \
  } while (0)

#define LDA(BUF, ROW, G) \
  (*reinterpret_cast<const int4v*>(&lds[(BUF)*65536 + (ROW)*128 + (((G) ^ ((ROW)&7)) << 4)]))
#define LDB(BUF, ROW, G) \
  (*reinterpret_cast<const int4v*>(&lds[(BUF)*65536 + 32768 + (ROW)*128 + (((G) ^ ((ROW)&7)) << 4)]))

#define MFMA16(MH, NH, AF, BF)                                                  \
  do {                                                                          \
    _Pragma("unroll") for (int kk = 0; kk < 2; ++kk)                            \
    _Pragma("unroll") for (int m = 0; m < 4; ++m)                               \
    _Pragma("unroll") for (int n = 0; n < 2; ++n)                               \
      acc[(MH)*4 + m][(NH)*2 + n] =                                             \
          MFMA_I8(AF[kk][m], BF[kk][n], acc[(MH)*4 + m][(NH)*2 + n]);           \
  } while (0)

  int4v acc[8][4];
#pragma unroll
  for (int mi = 0; mi < 8; ++mi)
#pragma unroll
    for (int ni = 0; ni < 4; ++ni) acc[mi][ni] = (int4v){0, 0, 0, 0};

  const int NT = K >> 7;
  const int ar = wm * 128 + (l & 15);
  const int br = wn * 64 + (l & 15);
  const int cr = l >> 4;

  STAGE2(Aq, aOff0, aOff1, 0);
  STAGE2(Aq, aOff0 + hstep, aOff1 + hstep, 16384);
  STAGE2(Bq, bOff0, bOff1, 32768);
  STAGE2(Bq, bOff0 + hstep, bOff1 + hstep, 49152);
  STAGE2(Aq, aOff0 + 128, aOff1 + 128, 65536);
  STAGE2(Aq, aOff0 + hstep + 128, aOff1 + hstep + 128, 65536 + 16384);

  for (int kt = 0; kt < NT; ++kt) {
    const int b = kt & 1, bn = b ^ 1;
    const size_t kO = (size_t)(kt + 1) * 128;
    const size_t kO2 = (size_t)(kt + 2) * 128;

    SCHED0();
    if (kt + 1 < NT) {
      asm volatile("s_waitcnt vmcnt(4)" ::: "memory");
    } else {
      asm volatile("s_waitcnt vmcnt(0)" ::: "memory");
    }
    SBAR();
    SCHED0();

    int4v aH[2][4], aC[2][4], b0[2][2], b1[2][2];

#pragma unroll
    for (int kk = 0; kk < 2; ++kk)
#pragma unroll
      for (int m = 0; m < 4; ++m) aH[kk][m] = LDA(b, ar + m * 16, kk * 4 + cr);
#pragma unroll
    for (int kk = 0; kk < 2; ++kk)
#pragma unroll
      for (int n = 0; n < 2; ++n) b0[kk][n] = LDB(b, br + n * 16, kk * 4 + cr);
    if (kt + 1 < NT) STAGE2(Bq, bOff0 + kO, bOff1 + kO, bn * 65536 + 32768);
    SCHED0(); SBAR(); SCHED0();
    __builtin_amdgcn_s_setprio(1);
    MFMA16(0, 0, aH, b0);
    __builtin_amdgcn_s_setprio(0);
    SCHED0(); SBAR(); SCHED0();

#pragma unroll
    for (int kk = 0; kk < 2; ++kk)
#pragma unroll
      for (int m = 0; m < 4; ++m) aC[kk][m] = LDA(b, ar + 64 + m * 16, kk * 4 + cr);
    if (kt + 1 < NT) STAGE2(Bq, bOff0 + hstep + kO, bOff1 + hstep + kO, bn * 65536 + 49152);
    SCHED0(); SBAR(); SCHED0();
    __builtin_amdgcn_s_setprio(1);
    MFMA16(1, 0, aC, b0);
    __builtin_amdgcn_s_setprio(0);
    SCHED0(); SBAR(); SCHED0();

#pragma unroll
    for (int kk = 0; kk < 2; ++kk)
#pragma unroll
      for (int n = 0; n < 2; ++n) b1[kk][n] = LDB(b, br + 32 + n * 16, kk * 4 + cr);
    if (kt + 2 < NT) STAGE2(Aq, aOff0 + kO2, aOff1 + kO2, b * 65536);
    SCHED0(); SBAR(); SCHED0();
    __builtin_amdgcn_s_setprio(1);
    MFMA16(1, 1, aC, b1);
    __builtin_amdgcn_s_setprio(0);
    SCHED0(); SBAR(); SCHED0();

    if (kt + 2 < NT) STAGE2(Aq, aOff0 + hstep + kO2, aOff1 + hstep + kO2, b * 65536 + 16384);
    SCHED0(); SBAR(); SCHED0();
    __builtin_amdgcn_s_setprio(1);
    MFMA16(0, 1, aH, b1);
    __builtin_amdgcn_s_setprio(0);
    SCHED0(); SBAR(); SCHED0();
  }

  const float sa = fmaxf(__uint_as_float(slots[sA]), 1e-8f) / 127.0f;
  const float sb = fmaxf(__uint_as_float(slots[sB]), 1e-8f) / 127.0f;
  const float s = sa * sb;
  const int crow0 = rowA0 + wm * 128 + ((l >> 4) << 2);
  const int ccol0 = colB0 + wn * 64 + (l & 15);
#pragma unroll
  for (int mi = 0; mi < 8; ++mi)
#pragma unroll
    for (int ni = 0; ni < 4; ++ni)
#pragma unroll
      for (int j = 0; j < 4; ++j) {
        const int row = crow0 + (mi >> 2) * 64 + (mi & 3) * 16 + j;
        const int col = ccol0 + (ni >> 1) * 32 + (ni & 1) * 16;
        C[(size_t)row * ldc + col] = (float)acc[mi][ni][j] * s;
      }
#undef STAGE2
#undef LDA
#undef LDB
#undef MFMA16
}

// ------------------------------------------------------------------- launch

extern "C" void kernel_launch(void* const* d_in, const int* in_sizes, int n_in,
                              void* d_out, int out_size, void* d_ws, size_t ws_size,
                              hipStream_t stream) {
  const float* x = (const float*)d_in[0];
  const float* w1 = (const float*)d_in[1];
  const float* w3 = (const float*)d_in[2];
  const float* w2 = (const float*)d_in[3];
  float* out = (float*)d_out;
  char* ws = (char*)d_ws;

  unsigned* slots = (unsigned*)ws;  // [0]=x [1]=w1 [2]=w3 [3]=w2 [4]=h absmax
  size_t off = 256;
  signed char* qx = (signed char*)(ws + off);
  off += (size_t)NTOK * DDIM;
  signed char* qw3 = (signed char*)(ws + off);
  off += (size_t)FDIM * DDIM;
  signed char* qw1 = (signed char*)(ws + off);
  off += (size_t)FDIM * DDIM;
  signed char* qw2 = (signed char*)(ws + off);
  off += (size_t)FDIM * DDIM;
  float* H = (float*)(ws + off);
  off += (size_t)NTOK * FDIM * 4;
  signed char* qh = (signed char*)(ws + off);
  off += (size_t)NTOK * FDIM;  // ~385 MB total

  const int n4x = NTOK * DDIM / 4;
  const int n4w = FDIM * DDIM / 4;
  const int n4h = NTOK * FDIM / 4;

  zero_slots<<<1, 64, 0, stream>>>(slots);
  absmax_kernel<<<2048, 256, 0, stream>>>(x, n4x, slots + 0);
  absmax_kernel<<<2048, 256, 0, stream>>>(w1, n4w, slots + 1);
  absmax_kernel<<<2048, 256, 0, stream>>>(w3, n4w, slots + 2);
  absmax_kernel<<<2048, 256, 0, stream>>>(w2, n4w, slots + 3);

  quant_kernel<<<2048, 256, 0, stream>>>(x, (unsigned*)qx, n4x, slots + 0);
  quant_kernel<<<2048, 256, 0, stream>>>(w1, (unsigned*)qw1, n4w, slots + 1);
  quant_kernel<<<2048, 256, 0, stream>>>(w3, (unsigned*)qw3, n4w, slots + 2);
  quant_kernel<<<2048, 256, 0, stream>>>(w2, (unsigned*)qw2, n4w, slots + 3);

  // fused gate+up: H = (x.w1^T*s1) * silu(x.w3^T*s3), + absmax(H)
  const dim3 gGlu(FDIM / 256, NTOK / 128);  // 43 x 32 = 1376 wgs (%8==0)
  gemm_glu<<<gGlu, 512, 0, stream>>>(qx, qw3, qw1, H, slots, slots + 4);
  quant_kernel<<<2048, 256, 0, stream>>>(H, (unsigned*)qh, n4h, slots + 4);
  // down: out = (h.w2^T) * s
  const dim3 gDn(DDIM / 256, NTOK / 256);  // 16 x 16 = 256 wgs
  gemm_down<<<gDn, 512, 0, stream>>>(qh, qw2, out, slots, 4, 3, FDIM, DDIM);
}

// Round 7
// 1037.871 us; speedup vs baseline: 1.2373x; 1.0052x over previous
//
#include <hip/hip_runtime.h>
#include <hip/hip_bf16.h>

typedef __attribute__((ext_vector_type(4))) int int4v;

#define MFMA_I8(a, b, c) __builtin_amdgcn_mfma_i32_16x16x64_i8((a), (b), (c), 0, 0, 0)
#define GLDS16(g, l)                                                                        \
  __builtin_amdgcn_global_load_lds((const __attribute__((address_space(1))) void*)(g),      \
                                   (__attribute__((address_space(3))) void*)(l), 16, 0, 0)
#define SBAR() __builtin_amdgcn_s_barrier()
#define SCHED0() __builtin_amdgcn_sched_barrier(0)

static constexpr int NTOK = 4096;
static constexpr int DDIM = 4096;
static constexpr int FDIM = 11008;

// ---------------------------------------------------------------- utilities

__device__ __forceinline__ float wave_max64(float m) {
#pragma unroll
  for (int o = 32; o > 0; o >>= 1) m = fmaxf(m, __shfl_xor(m, o));
  return m;
}

__global__ void zero_slots(unsigned* s) {
  if (threadIdx.x < 16) s[threadIdx.x] = 0u;
}

__global__ void absmax_kernel(const float* __restrict__ p, int n4, unsigned* __restrict__ slot) {
  float m = 0.f;
  const int stride = gridDim.x * blockDim.x;
  for (int i = blockIdx.x * blockDim.x + threadIdx.x; i < n4; i += stride) {
    float4 v = reinterpret_cast<const float4*>(p)[i];
    m = fmaxf(fmaxf(fabsf(v.x), fabsf(v.y)), fmaxf(fmaxf(fabsf(v.z), fabsf(v.w)), m));
  }
  m = wave_max64(m);
  __shared__ float wm[4];
  const int lane = threadIdx.x & 63, w = threadIdx.x >> 6;
  if (lane == 0) wm[w] = m;
  __syncthreads();
  if (threadIdx.x == 0) {
    m = fmaxf(fmaxf(wm[0], wm[1]), fmaxf(wm[2], wm[3]));
    atomicMax(slot, __float_as_uint(m));
  }
}

// q = rint(t / s) as signed i8, 4 packed per u32 (|q| <= 127, exact)
__global__ void quant_kernel(const float* __restrict__ in, unsigned* __restrict__ out,
                             int n4, const unsigned* __restrict__ slot) {
  const float s = fmaxf(__uint_as_float(*slot), 1e-8f) / 127.0f;
  const int stride = gridDim.x * blockDim.x;
  for (int i = blockIdx.x * blockDim.x + threadIdx.x; i < n4; i += stride) {
    float4 v = reinterpret_cast<const float4*>(in)[i];
    const int q0 = (int)rintf(v.x / s), q1 = (int)rintf(v.y / s);
    const int q2 = (int)rintf(v.z / s), q3 = (int)rintf(v.w / s);
    out[i] = (unsigned)(q0 & 255) | ((unsigned)(q1 & 255) << 8) |
             ((unsigned)(q2 & 255) << 16) | ((unsigned)(q3 & 255) << 24);
  }
}

// ------------------------------------- fused gate+up GLU GEMM, triple-buffer
// H[M][F] = (A.B1^T*s1) * silu(A.B3^T*s3); A=qx[128-tile][K], B3/B1=[F][K] i8.
// Tile 128x256, 8 waves (2M x 4N), per-wave 64x64 per output tensor.
// BK=64. LDS = 3 bufs x 40960 B {A[128][64] @0, B3[256][64] @8192,
// B1[256][64] @24576}. Tile kt reads buf kt%3; stages tile kt+2 into buf
// (kt+2)%3 -> staging target never touches a buffer anyone reads until two
// boundaries later => ONE barrier + one counted vmcnt per tile, no intra-tile
// barriers; compiler freely interleaves ds_read / stage / MFMA (fine lgkm).
// Boundary: vmcnt(5) keeps tile kt+1's 5 loads in flight (2-tile cover).
// Swizzle: 16B granule g^((row>>1)&3) on global source + ds_read (2-way max).
__global__ __launch_bounds__(512, 2) void gemm_glu(
    const signed char* __restrict__ Aq, const signed char* __restrict__ B3q,
    const signed char* __restrict__ B1q, float* __restrict__ H,
    const unsigned* __restrict__ slots, unsigned* __restrict__ hslot) {
  constexpr int K = DDIM;
  __shared__ char lds[122880];  // 3 x 40960

  const int t = threadIdx.x;
  const int l = t & 63;
  const int w = t >> 6;   // wave 0..7
  const int wm = w >> 2;  // 0..1 (M)
  const int wn = w & 3;   // 0..3 (N)

  // XCD-aware column-major chunking (nwg = 43*32 = 1376, %8==0)
  const int gx = gridDim.x, gy = gridDim.y;
  const int nwg = gx * gy;
  const int i0 = blockIdx.y * gx + blockIdx.x;
  const int cid = (i0 & 7) * (nwg >> 3) + (i0 >> 3);
  const int rowA0 = (cid % gy) << 7;  // 128-row tile
  const int colB0 = (cid / gy) << 8;  // 256-col tile

  // staging: thread t covers local row t>>2, pre-swizzled 16B granule
  const int rl = t >> 2;                   // 0..127
  const int gl = (t & 3) ^ ((t >> 3) & 3); // (rl>>1)&3 == (t>>3)&3
  const signed char* aP = Aq + (size_t)(rowA0 + rl) * K + gl * 16;
  const signed char* b3P = B3q + (size_t)(colB0 + rl) * K + gl * 16;
  const signed char* b1P = B1q + (size_t)(colB0 + rl) * K + gl * 16;
  const size_t rstep = (size_t)128 * K;
  const int stW = w * 1024;

// stage tile (5 loads, fixed order A,B3x2,B1x2 for vmcnt accounting)
#define STAGE5(KO, BASE)                                          \
  do {                                                            \
    GLDS16(aP + (KO), &lds[(BASE) + stW]);                        \
    GLDS16(b3P + (KO), &lds[(BASE) + 8192 + stW]);                \
    GLDS16(b3P + rstep + (KO), &lds[(BASE) + 16384 + stW]);       \
    GLDS16(b1P + (KO), &lds[(BASE) + 24576 + stW]);               \
    GLDS16(b1P + rstep + (KO), &lds[(BASE) + 32768 + stW]);       \
  } while (0)

#define LDSF(BASE, ROW)                                                       \
  (*reinterpret_cast<const int4v*>(                                           \
      &lds[(BASE) + (ROW)*64 + (((l >> 4) ^ (((ROW) >> 1) & 3)) << 4)]))

  int4v acc3[4][4], acc1[4][4];
#pragma unroll
  for (int m = 0; m < 4; ++m)
#pragma unroll
    for (int n = 0; n < 4; ++n) {
      acc3[m][n] = (int4v){0, 0, 0, 0};
      acc1[m][n] = (int4v){0, 0, 0, 0};
    }

  const int NT = K >> 6;  // 64
  const int arow = wm * 64 + (l & 15);
  const int brow = wn * 64 + (l & 15);

  // prologue: tile0 -> buf0, tile1 -> buf1
  STAGE5(0, 0);
  STAGE5(64, 40960);

  int rb = 0, sb = 81920;
  for (int kt = 0; kt < NT; ++kt) {
    // ---- boundary: tile kt landed; kt+1's 5 loads stay in flight
    SCHED0();
    if (kt + 1 < NT) {
      asm volatile("s_waitcnt vmcnt(5)" ::: "memory");
    } else {
      asm volatile("s_waitcnt vmcnt(0)" ::: "memory");
    }
    SBAR();
    SCHED0();  // pin: nothing moves across the tile boundary

    int4v a[4], b3f[4], b1f[4];
#pragma unroll
    for (int m = 0; m < 4; ++m) a[m] = LDSF(rb, arow + m * 16);
#pragma unroll
    for (int n = 0; n < 4; ++n) b3f[n] = LDSF(rb + 8192, brow + n * 16);
#pragma unroll
    for (int n = 0; n < 4; ++n) b1f[n] = LDSF(rb + 24576, brow + n * 16);
    if (kt + 2 < NT) STAGE5((size_t)(kt + 2) * 64, sb);

    __builtin_amdgcn_s_setprio(1);
#pragma unroll
    for (int m = 0; m < 4; ++m)
#pragma unroll
      for (int n = 0; n < 4; ++n) acc3[m][n] = MFMA_I8(a[m], b3f[n], acc3[m][n]);
#pragma unroll
    for (int m = 0; m < 4; ++m)
#pragma unroll
      for (int n = 0; n < 4; ++n) acc1[m][n] = MFMA_I8(a[m], b1f[n], acc1[m][n]);
    __builtin_amdgcn_s_setprio(0);

    rb = (rb == 81920) ? 0 : rb + 40960;
    sb = (sb == 81920) ? 0 : sb + 40960;
  }

  // ------------------------------------------------------------- epilogue
  const float sx = fmaxf(__uint_as_float(slots[0]), 1e-8f) / 127.0f;
  const float sw1 = fmaxf(__uint_as_float(slots[1]), 1e-8f) / 127.0f;
  const float sw3 = fmaxf(__uint_as_float(slots[2]), 1e-8f) / 127.0f;
  const float s3 = sx * sw3, s1 = sx * sw1;
  const int crow0 = rowA0 + wm * 64 + ((l >> 4) << 2);
  const int ccol0 = colB0 + wn * 64 + (l & 15);
  float hmax = 0.f;
#pragma unroll
  for (int m = 0; m < 4; ++m)
#pragma unroll
    for (int n = 0; n < 4; ++n)
#pragma unroll
      for (int j = 0; j < 4; ++j) {
        const int row = crow0 + m * 16 + j;
        const int col = ccol0 + n * 16;
        const float g = (float)acc3[m][n][j] * s3;
        const float gate = g / (1.f + expf(-g));  // silu
        const float h = (float)acc1[m][n][j] * s1 * gate;
        H[(size_t)row * FDIM + col] = h;
        hmax = fmaxf(hmax, fabsf(h));
      }
  hmax = wave_max64(hmax);
  if (l == 0) atomicMax(hslot, __float_as_uint(hmax));
#undef STAGE5
#undef LDSF
}

// ---------------------------------------- 256x256 down GEMM, triple-buffer
// out[M][N] = s * A[M][K].B[N][K]^T, same one-barrier/tile structure.
// 8 waves (2M x 4N), per-wave 128x64. BK=64. LDS = 3 x 32768 B
// {A[256][64] @0, B[256][64] @16384}. Stage tile kt+2 (4 loads); vmcnt(4).
__global__ __launch_bounds__(512, 2) void gemm_down(
    const signed char* __restrict__ Aq, const signed char* __restrict__ Bq,
    float* __restrict__ C, const unsigned* __restrict__ slots, int sA, int sB,
    int K, int ldc) {
  __shared__ char lds[98304];  // 3 x 32768

  const int t = threadIdx.x;
  const int l = t & 63;
  const int w = t >> 6;
  const int wm = w >> 2;  // 0..1
  const int wn = w & 3;   // 0..3

  const int gx = gridDim.x, gy = gridDim.y;
  const int nwg = gx * gy;
  const int i0 = blockIdx.y * gx + blockIdx.x;
  const int cid = (i0 & 7) * (nwg >> 3) + (i0 >> 3);
  const int rowA0 = (cid % gy) << 8;
  const int colB0 = (cid / gy) << 8;

  const int rl = t >> 2;
  const int gl = (t & 3) ^ ((t >> 3) & 3);
  const signed char* aP = Aq + (size_t)(rowA0 + rl) * K + gl * 16;
  const signed char* bP = Bq + (size_t)(colB0 + rl) * K + gl * 16;
  const size_t rstep = (size_t)128 * K;
  const int stW = w * 1024;

#define STAGE4(KO, BASE)                                          \
  do {                                                            \
    GLDS16(aP + (KO), &lds[(BASE) + stW]);                        \
    GLDS16(aP + rstep + (KO), &lds[(BASE) + 8192 + stW]);         \
    GLDS16(bP + (KO), &lds[(BASE) + 16384 + stW]);                \
    GLDS16(bP + rstep + (KO), &lds[(BASE) + 24576 + stW]);        \
  } while (0)

#define LDSF(BASE, ROW)                                                       \
  (*reinterpret_cast<const int4v*>(                                           \
      &lds[(BASE) + (ROW)*64 + (((l >> 4) ^ (((ROW) >> 1) & 3)) << 4)]))

  int4v acc[8][4];
#pragma unroll
  for (int m = 0; m < 8; ++m)
#pragma unroll
    for (int n = 0; n < 4; ++n) acc[m][n] = (int4v){0, 0, 0, 0};

  const int NT = K >> 6;  // 172
  const int arow = wm * 128 + (l & 15);
  const int brow = wn * 64 + (l & 15);

  STAGE4(0, 0);
  STAGE4(64, 32768);

  int rb = 0, sb = 65536;
  for (int kt = 0; kt < NT; ++kt) {
    SCHED0();
    if (kt + 1 < NT) {
      asm volatile("s_waitcnt vmcnt(4)" ::: "memory");
    } else {
      asm volatile("s_waitcnt vmcnt(0)" ::: "memory");
    }
    SBAR();
    SCHED0();

    int4v a[8], b[4];
#pragma unroll
    for (int m = 0; m < 8; ++m) a[m] = LDSF(rb, arow + m * 16);
#pragma unroll
    for (int n = 0; n < 4; ++n) b[n] = LDSF(rb + 16384, brow + n * 16);
    if (kt + 2 < NT) STAGE4((size_t)(kt + 2) * 64, sb);

    __builtin_amdgcn_s_setprio(1);
#pragma unroll
    for (int m = 0; m < 8; ++m)
#pragma unroll
      for (int n = 0; n < 4; ++n) acc[m][n] = MFMA_I8(a[m], b[n], acc[m][n]);
    __builtin_amdgcn_s_setprio(0);

    rb = (rb == 65536) ? 0 : rb + 32768;
    sb = (sb == 65536) ? 0 : sb + 32768;
  }

  const float sa = fmaxf(__uint_as_float(slots[sA]), 1e-8f) / 127.0f;
  const float sb2 = fmaxf(__uint_as_float(slots[sB]), 1e-8f) / 127.0f;
  const float s = sa * sb2;
  const int crow0 = rowA0 + wm * 128 + ((l >> 4) << 2);
  const int ccol0 = colB0 + wn * 64 + (l & 15);
#pragma unroll
  for (int m = 0; m < 8; ++m)
#pragma unroll
    for (int n = 0; n < 4; ++n)
#pragma unroll
      for (int j = 0; j < 4; ++j) {
        const int row = crow0 + m * 16 + j;
        const int col = ccol0 + n * 16;
        C[(size_t)row * ldc + col] = (float)acc[m][n][j] * s;
      }
#undef STAGE4
#undef LDSF
}

// ------------------------------------------------------------------- launch

extern "C" void kernel_launch(void* const* d_in, const int* in_sizes, int n_in,
                              void* d_out, int out_size, void* d_ws, size_t ws_size,
                              hipStream_t stream) {
  const float* x = (const float*)d_in[0];
  const float* w1 = (const float*)d_in[1];
  const float* w3 = (const float*)d_in[2];
  const float* w2 = (const float*)d_in[3];
  float* out = (float*)d_out;
  char* ws = (char*)d_ws;

  unsigned* slots = (unsigned*)ws;  // [0]=x [1]=w1 [2]=w3 [3]=w2 [4]=h absmax
  size_t off = 256;
  signed char* qx = (signed char*)(ws + off);
  off += (size_t)NTOK * DDIM;
  signed char* qw3 = (signed char*)(ws + off);
  off += (size_t)FDIM * DDIM;
  signed char* qw1 = (signed char*)(ws + off);
  off += (size_t)FDIM * DDIM;
  signed char* qw2 = (signed char*)(ws + off);
  off += (size_t)FDIM * DDIM;
  float* H = (float*)(ws + off);
  off += (size_t)NTOK * FDIM * 4;
  signed char* qh = (signed char*)(ws + off);
  off += (size_t)NTOK * FDIM;  // ~385 MB total

  const int n4x = NTOK * DDIM / 4;
  const int n4w = FDIM * DDIM / 4;
  const int n4h = NTOK * FDIM / 4;

  zero_slots<<<1, 64, 0, stream>>>(slots);
  absmax_kernel<<<2048, 256, 0, stream>>>(x, n4x, slots + 0);
  absmax_kernel<<<2048, 256, 0, stream>>>(w1, n4w, slots + 1);
  absmax_kernel<<<2048, 256, 0, stream>>>(w3, n4w, slots + 2);
  absmax_kernel<<<2048, 256, 0, stream>>>(w2, n4w, slots + 3);

  quant_kernel<<<2048, 256, 0, stream>>>(x, (unsigned*)qx, n4x, slots + 0);
  quant_kernel<<<2048, 256, 0, stream>>>(w1, (unsigned*)qw1, n4w, slots + 1);
  quant_kernel<<<2048, 256, 0, stream>>>(w3, (unsigned*)qw3, n4w, slots + 2);
  quant_kernel<<<2048, 256, 0, stream>>>(w2, (unsigned*)qw2, n4w, slots + 3);

  // fused gate+up: H = (x.w1^T*s1) * silu(x.w3^T*s3), + absmax(H)
  const dim3 gGlu(FDIM / 256, NTOK / 128);  // 43 x 32 = 1376 wgs
  gemm_glu<<<gGlu, 512, 0, stream>>>(qx, qw3, qw1, H, slots, slots + 4);
  quant_kernel<<<2048, 256, 0, stream>>>(H, (unsigned*)qh, n4h, slots + 4);
  // down: out = (h.w2^T) * s
  const dim3 gDn(DDIM / 256, NTOK / 256);  // 16 x 16 = 256 wgs
  gemm_down<<<gDn, 512, 0, stream>>>(qh, qw2, out, slots, 4, 3, FDIM, DDIM);
}

// Round 8
// 906.672 us; speedup vs baseline: 1.4163x; 1.1447x over previous
//
#include <hip/hip_runtime.h>
#include <hip/hip_bf16.h>

typedef __attribute__((ext_vector_type(4))) int int4v;

#define MFMA_I8(a, b, c) __builtin_amdgcn_mfma_i32_16x16x64_i8((a), (b), (c), 0, 0, 0)
#define GLDS16(g, l)                                                                        \
  __builtin_amdgcn_global_load_lds((const __attribute__((address_space(1))) void*)(g),      \
                                   (__attribute__((address_space(3))) void*)(l), 16, 0, 0)
#define SBAR() __builtin_amdgcn_s_barrier()
#define SCHED0() __builtin_amdgcn_sched_barrier(0)

static constexpr int NTOK = 4096;
static constexpr int DDIM = 4096;
static constexpr int FDIM = 11008;

// ---------------------------------------------------------------- utilities

__device__ __forceinline__ float wave_max64(float m) {
#pragma unroll
  for (int o = 32; o > 0; o >>= 1) m = fmaxf(m, __shfl_xor(m, o));
  return m;
}

__global__ void zero_slots(unsigned* s) {
  if (threadIdx.x < 16) s[threadIdx.x] = 0u;
}

__device__ __forceinline__ void absmax_body(const float* __restrict__ p, int n4,
                                            unsigned* __restrict__ slot) {
  float m = 0.f;
  const int stride = gridDim.x * blockDim.x;
  for (int i = blockIdx.x * blockDim.x + threadIdx.x; i < n4; i += stride) {
    float4 v = reinterpret_cast<const float4*>(p)[i];
    m = fmaxf(fmaxf(fabsf(v.x), fabsf(v.y)), fmaxf(fmaxf(fabsf(v.z), fabsf(v.w)), m));
  }
  m = wave_max64(m);
  __shared__ float wm[4];
  const int lane = threadIdx.x & 63, w = threadIdx.x >> 6;
  if (lane == 0) wm[w] = m;
  __syncthreads();
  if (threadIdx.x == 0) {
    m = fmaxf(fmaxf(wm[0], wm[1]), fmaxf(wm[2], wm[3]));
    atomicMax(slot, __float_as_uint(m));
  }
}

// 4 tensors in one launch: blockIdx.y picks the tensor
__global__ void absmax4(const float* x, const float* w1, const float* w3, const float* w2,
                        unsigned* slots, int n4x, int n4w) {
  const int seg = blockIdx.y;
  const float* p = (seg == 0) ? x : (seg == 1) ? w1 : (seg == 2) ? w3 : w2;
  absmax_body(p, seg == 0 ? n4x : n4w, slots + seg);
}

__device__ __forceinline__ void quant_body(const float* __restrict__ in,
                                           unsigned* __restrict__ out, int n4,
                                           const unsigned* __restrict__ slot) {
  const float s = fmaxf(__uint_as_float(*slot), 1e-8f) / 127.0f;
  const int stride = gridDim.x * blockDim.x;
  for (int i = blockIdx.x * blockDim.x + threadIdx.x; i < n4; i += stride) {
    float4 v = reinterpret_cast<const float4*>(in)[i];
    const int q0 = (int)rintf(v.x / s), q1 = (int)rintf(v.y / s);
    const int q2 = (int)rintf(v.z / s), q3 = (int)rintf(v.w / s);
    out[i] = (unsigned)(q0 & 255) | ((unsigned)(q1 & 255) << 8) |
             ((unsigned)(q2 & 255) << 16) | ((unsigned)(q3 & 255) << 24);
  }
}

__global__ void quant4(const float* x, const float* w1, const float* w3, const float* w2,
                       unsigned* qx, unsigned* qw1, unsigned* qw3, unsigned* qw2,
                       const unsigned* slots, int n4x, int n4w) {
  const int seg = blockIdx.y;
  const float* p = (seg == 0) ? x : (seg == 1) ? w1 : (seg == 2) ? w3 : w2;
  unsigned* o = (seg == 0) ? qx : (seg == 1) ? qw1 : (seg == 2) ? qw3 : qw2;
  quant_body(p, o, seg == 0 ? n4x : n4w, slots + seg);
}

__global__ void quant_kernel(const float* __restrict__ in, unsigned* __restrict__ out,
                             int n4, const unsigned* __restrict__ slot) {
  quant_body(in, out, n4, slot);
}

// --------------------------- fused gate+up GLU GEMM, BK=128, 1 barrier/tile
// H[M][F] = (A.B1^T*s1)*silu(A.B3^T*s3); A[128-tile][K], B3/B1[F][K] i8.
// Tile 128x256, 8 waves (2M x 4N), per-wave 64x64 per tensor (acc=128 VGPR).
// BK=128 (128 B/row). LDS = 2 bufs x 81920 B {A[128][128] @0, B3[256][128]
// @16384, B1[256][128] @49152} = 160 KiB (full pool).  Per tile: ONE
// boundary {vmcnt(0); s_barrier}; then stage tile kt+1 -> other buf
// (its readers finished before the PREVIOUS boundary); then 2 kk-slices of
// {12 ds_read_b128 + 32 MFMA}. 64 MFMA per wave per barrier.
// Swizzle: 16B granule g_phys = g ^ (row&7) on global source + ds_read.
__global__ __launch_bounds__(512, 2) void gemm_glu(
    const signed char* __restrict__ Aq, const signed char* __restrict__ B3q,
    const signed char* __restrict__ B1q, float* __restrict__ H,
    const unsigned* __restrict__ slots, unsigned* __restrict__ hslot) {
  constexpr int K = DDIM;
  __shared__ char lds[163840];  // 2 x 81920 = 160 KiB

  const int t = threadIdx.x;
  const int l = t & 63;
  const int w = t >> 6;   // wave 0..7
  const int wm = w >> 2;  // 0..1 (M)
  const int wn = w & 3;   // 0..3 (N)

  // XCD-aware column-major chunking (nwg = 43*32 = 1376, %8==0)
  const int gx = gridDim.x, gy = gridDim.y;
  const int nwg = gx * gy;
  const int i0 = blockIdx.y * gx + blockIdx.x;
  const int cid = (i0 & 7) * (nwg >> 3) + (i0 >> 3);
  const int rowA0 = (cid % gy) << 7;  // 128-row tile
  const int colB0 = (cid / gy) << 8;  // 256-col tile

  // staging: thread t covers local row t>>3 (64 rows/instr), pre-swizzled
  const int rl = t >> 3;                   // 0..63 (row % 64; +64k keeps row&7)
  const int gl = (t & 7) ^ (rl & 7);       // pre-swizzled 16B granule (0..7)
  const signed char* aP = Aq + (size_t)(rowA0 + rl) * K + gl * 16;
  const signed char* b3P = B3q + (size_t)(colB0 + rl) * K + gl * 16;
  const signed char* b1P = B1q + (size_t)(colB0 + rl) * K + gl * 16;
  const size_t r64 = (size_t)64 * K;
  const int stW = w * 1024;  // wave-uniform LDS slice (64 lanes x 16B)

// stage one full tile (10 x global_load_lds_dwordx4) into buffer BASE
#define STAGE10(KO, BASE)                                            \
  do {                                                               \
    GLDS16(aP + (KO), &lds[(BASE) + stW]);                           \
    GLDS16(aP + r64 + (KO), &lds[(BASE) + 8192 + stW]);              \
    GLDS16(b3P + (KO), &lds[(BASE) + 16384 + stW]);                  \
    GLDS16(b3P + r64 + (KO), &lds[(BASE) + 24576 + stW]);            \
    GLDS16(b3P + 2 * r64 + (KO), &lds[(BASE) + 32768 + stW]);        \
    GLDS16(b3P + 3 * r64 + (KO), &lds[(BASE) + 40960 + stW]);        \
    GLDS16(b1P + (KO), &lds[(BASE) + 49152 + stW]);                  \
    GLDS16(b1P + r64 + (KO), &lds[(BASE) + 57344 + stW]);            \
    GLDS16(b1P + 2 * r64 + (KO), &lds[(BASE) + 65536 + stW]);        \
    GLDS16(b1P + 3 * r64 + (KO), &lds[(BASE) + 73728 + stW]);        \
  } while (0)

// swizzled frag read: BASE = region byte base, ROW local, G logical granule
#define LDSF(BASE, ROW, G)                                                    \
  (*reinterpret_cast<const int4v*>(                                           \
      &lds[(BASE) + (ROW)*128 + (((G) ^ ((ROW)&7)) << 4)]))

  int4v acc3[4][4], acc1[4][4];
#pragma unroll
  for (int m = 0; m < 4; ++m)
#pragma unroll
    for (int n = 0; n < 4; ++n) {
      acc3[m][n] = (int4v){0, 0, 0, 0};
      acc1[m][n] = (int4v){0, 0, 0, 0};
    }

  const int NT = K >> 7;  // 32
  const int arow = wm * 64 + (l & 15);
  const int brow = wn * 64 + (l & 15);
  const int cr = l >> 4;  // granule base within kk-slice (0..3)

  STAGE10(0, 0);  // tile 0 -> buf 0

  for (int kt = 0; kt < NT; ++kt) {
    const int rb = (kt & 1) * 81920;
    // ---- boundary: tile kt fully in LDS
    SCHED0();
    asm volatile("s_waitcnt vmcnt(0)" ::: "memory");
    SBAR();
    SCHED0();

    // stage next tile into the other buffer (readers done pre-prev-boundary)
    if (kt + 1 < NT) STAGE10((size_t)(kt + 1) * 128, rb ^ 81920);

#pragma unroll
    for (int kk = 0; kk < 2; ++kk) {
      int4v a[4], b3f[4], b1f[4];
#pragma unroll
      for (int m = 0; m < 4; ++m) a[m] = LDSF(rb, arow + m * 16, kk * 4 + cr);
#pragma unroll
      for (int n = 0; n < 4; ++n) b3f[n] = LDSF(rb + 16384, brow + n * 16, kk * 4 + cr);
#pragma unroll
      for (int n = 0; n < 4; ++n) b1f[n] = LDSF(rb + 49152, brow + n * 16, kk * 4 + cr);
      __builtin_amdgcn_s_setprio(1);
#pragma unroll
      for (int m = 0; m < 4; ++m)
#pragma unroll
        for (int n = 0; n < 4; ++n) acc3[m][n] = MFMA_I8(a[m], b3f[n], acc3[m][n]);
#pragma unroll
      for (int m = 0; m < 4; ++m)
#pragma unroll
        for (int n = 0; n < 4; ++n) acc1[m][n] = MFMA_I8(a[m], b1f[n], acc1[m][n]);
      __builtin_amdgcn_s_setprio(0);
    }
  }

  // ------------------------------------------------------------- epilogue
  const float sx = fmaxf(__uint_as_float(slots[0]), 1e-8f) / 127.0f;
  const float sw1 = fmaxf(__uint_as_float(slots[1]), 1e-8f) / 127.0f;
  const float sw3 = fmaxf(__uint_as_float(slots[2]), 1e-8f) / 127.0f;
  const float s3 = sx * sw3, s1 = sx * sw1;
  const int crow0 = rowA0 + wm * 64 + ((l >> 4) << 2);
  const int ccol0 = colB0 + wn * 64 + (l & 15);
  float hmax = 0.f;
#pragma unroll
  for (int m = 0; m < 4; ++m)
#pragma unroll
    for (int n = 0; n < 4; ++n)
#pragma unroll
      for (int j = 0; j < 4; ++j) {
        const int row = crow0 + m * 16 + j;
        const int col = ccol0 + n * 16;
        const float g = (float)acc3[m][n][j] * s3;
        const float gate = g / (1.f + expf(-g));  // silu
        const float h = (float)acc1[m][n][j] * s1 * gate;
        H[(size_t)row * FDIM + col] = h;
        hmax = fmaxf(hmax, fabsf(h));
      }
  hmax = wave_max64(hmax);
  if (l == 0) atomicMax(hslot, __float_as_uint(hmax));
#undef STAGE10
#undef LDSF
}

// ------------------------------- 256x256 down GEMM, BK=128, 1 barrier/tile
// out[M][N] = s * A[M][K].B[N][K]^T.  8 waves (2M x 4N), per-wave 128x64
// (acc = 128 VGPR). LDS = 2 bufs x 65536 {A[256][128] @0, B[256][128]
// @32768}. Same dbuf one-barrier schedule; 8 staging loads/tile.
__global__ __launch_bounds__(512, 2) void gemm_down(
    const signed char* __restrict__ Aq, const signed char* __restrict__ Bq,
    float* __restrict__ C, const unsigned* __restrict__ slots, int sA, int sB,
    int K, int ldc) {
  __shared__ char lds[131072];  // 2 x 65536

  const int t = threadIdx.x;
  const int l = t & 63;
  const int w = t >> 6;
  const int wm = w >> 2;  // 0..1
  const int wn = w & 3;   // 0..3

  const int gx = gridDim.x, gy = gridDim.y;
  const int nwg = gx * gy;
  const int i0 = blockIdx.y * gx + blockIdx.x;
  const int cid = (i0 & 7) * (nwg >> 3) + (i0 >> 3);
  const int rowA0 = (cid % gy) << 8;
  const int colB0 = (cid / gy) << 8;

  const int rl = t >> 3;
  const int gl = (t & 7) ^ (rl & 7);
  const signed char* aP = Aq + (size_t)(rowA0 + rl) * K + gl * 16;
  const signed char* bP = Bq + (size_t)(colB0 + rl) * K + gl * 16;
  const size_t r64 = (size_t)64 * K;
  const int stW = w * 1024;

#define STAGE8(KO, BASE)                                             \
  do {                                                               \
    GLDS16(aP + (KO), &lds[(BASE) + stW]);                           \
    GLDS16(aP + r64 + (KO), &lds[(BASE) + 8192 + stW]);              \
    GLDS16(aP + 2 * r64 + (KO), &lds[(BASE) + 16384 + stW]);         \
    GLDS16(aP + 3 * r64 + (KO), &lds[(BASE) + 24576 + stW]);         \
    GLDS16(bP + (KO), &lds[(BASE) + 32768 + stW]);                   \
    GLDS16(bP + r64 + (KO), &lds[(BASE) + 40960 + stW]);             \
    GLDS16(bP + 2 * r64 + (KO), &lds[(BASE) + 49152 + stW]);         \
    GLDS16(bP + 3 * r64 + (KO), &lds[(BASE) + 57344 + stW]);         \
  } while (0)

#define LDSF(BASE, ROW, G)                                                    \
  (*reinterpret_cast<const int4v*>(                                           \
      &lds[(BASE) + (ROW)*128 + (((G) ^ ((ROW)&7)) << 4)]))

  int4v acc[8][4];
#pragma unroll
  for (int m = 0; m < 8; ++m)
#pragma unroll
    for (int n = 0; n < 4; ++n) acc[m][n] = (int4v){0, 0, 0, 0};

  const int NT = K >> 7;  // 86
  const int arow = wm * 128 + (l & 15);
  const int brow = wn * 64 + (l & 15);
  const int cr = l >> 4;

  STAGE8(0, 0);

  for (int kt = 0; kt < NT; ++kt) {
    const int rb = (kt & 1) * 65536;
    SCHED0();
    asm volatile("s_waitcnt vmcnt(0)" ::: "memory");
    SBAR();
    SCHED0();

    if (kt + 1 < NT) STAGE8((size_t)(kt + 1) * 128, rb ^ 65536);

#pragma unroll
    for (int kk = 0; kk < 2; ++kk) {
      int4v a[8], b[4];
#pragma unroll
      for (int m = 0; m < 8; ++m) a[m] = LDSF(rb, arow + m * 16, kk * 4 + cr);
#pragma unroll
      for (int n = 0; n < 4; ++n) b[n] = LDSF(rb + 32768, brow + n * 16, kk * 4 + cr);
      __builtin_amdgcn_s_setprio(1);
#pragma unroll
      for (int m = 0; m < 8; ++m)
#pragma unroll
        for (int n = 0; n < 4; ++n) acc[m][n] = MFMA_I8(a[m], b[n], acc[m][n]);
      __builtin_amdgcn_s_setprio(0);
    }
  }

  const float sa = fmaxf(__uint_as_float(slots[sA]), 1e-8f) / 127.0f;
  const float sb2 = fmaxf(__uint_as_float(slots[sB]), 1e-8f) / 127.0f;
  const float s = sa * sb2;
  const int crow0 = rowA0 + wm * 128 + ((l >> 4) << 2);
  const int ccol0 = colB0 + wn * 64 + (l & 15);
#pragma unroll
  for (int m = 0; m < 8; ++m)
#pragma unroll
    for (int n = 0; n < 4; ++n)
#pragma unroll
      for (int j = 0; j < 4; ++j) {
        const int row = crow0 + m * 16 + j;
        const int col = ccol0 + n * 16;
        C[(size_t)row * ldc + col] = (float)acc[m][n][j] * s;
      }
#undef STAGE8
#undef LDSF
}

// ------------------------------------------------------------------- launch

extern "C" void kernel_launch(void* const* d_in, const int* in_sizes, int n_in,
                              void* d_out, int out_size, void* d_ws, size_t ws_size,
                              hipStream_t stream) {
  const float* x = (const float*)d_in[0];
  const float* w1 = (const float*)d_in[1];
  const float* w3 = (const float*)d_in[2];
  const float* w2 = (const float*)d_in[3];
  float* out = (float*)d_out;
  char* ws = (char*)d_ws;

  unsigned* slots = (unsigned*)ws;  // [0]=x [1]=w1 [2]=w3 [3]=w2 [4]=h absmax
  size_t off = 256;
  signed char* qx = (signed char*)(ws + off);
  off += (size_t)NTOK * DDIM;
  signed char* qw3 = (signed char*)(ws + off);
  off += (size_t)FDIM * DDIM;
  signed char* qw1 = (signed char*)(ws + off);
  off += (size_t)FDIM * DDIM;
  signed char* qw2 = (signed char*)(ws + off);
  off += (size_t)FDIM * DDIM;
  float* H = (float*)(ws + off);
  off += (size_t)NTOK * FDIM * 4;
  signed char* qh = (signed char*)(ws + off);
  off += (size_t)NTOK * FDIM;  // ~385 MB total

  const int n4x = NTOK * DDIM / 4;
  const int n4w = FDIM * DDIM / 4;
  const int n4h = NTOK * FDIM / 4;

  zero_slots<<<1, 64, 0, stream>>>(slots);
  absmax4<<<dim3(512, 4), 256, 0, stream>>>(x, w1, w3, w2, slots, n4x, n4w);
  quant4<<<dim3(512, 4), 256, 0, stream>>>(x, w1, w3, w2, (unsigned*)qx, (unsigned*)qw1,
                                           (unsigned*)qw3, (unsigned*)qw2, slots, n4x, n4w);

  // fused gate+up: H = (x.w1^T*s1) * silu(x.w3^T*s3), + absmax(H)
  const dim3 gGlu(FDIM / 256, NTOK / 128);  // 43 x 32 = 1376 wgs
  gemm_glu<<<gGlu, 512, 0, stream>>>(qx, qw3, qw1, H, slots, slots + 4);
  quant_kernel<<<2048, 256, 0, stream>>>(H, (unsigned*)qh, n4h, slots + 4);
  // down: out = (h.w2^T) * s
  const dim3 gDn(DDIM / 256, NTOK / 256);  // 16 x 16 = 256 wgs
  gemm_down<<<gDn, 512, 0, stream>>>(qh, qw2, out, slots, 4, 3, FDIM, DDIM);
}

// Round 9
// 893.036 us; speedup vs baseline: 1.4380x; 1.0153x over previous
//
#include <hip/hip_runtime.h>
#include <hip/hip_bf16.h>

typedef __attribute__((ext_vector_type(4))) int int4v;

#define MFMA_I8(a, b, c) __builtin_amdgcn_mfma_i32_16x16x64_i8((a), (b), (c), 0, 0, 0)
#define GLDS16(g, l)                                                                        \
  __builtin_amdgcn_global_load_lds((const __attribute__((address_space(1))) void*)(g),      \
                                   (__attribute__((address_space(3))) void*)(l), 16, 0, 0)
#define SBAR() __builtin_amdgcn_s_barrier()
#define SCHED0() __builtin_amdgcn_sched_barrier(0)

static constexpr int NTOK = 4096;
static constexpr int DDIM = 4096;
static constexpr int FDIM = 11008;

// ---------------------------------------------------------------- utilities

__device__ __forceinline__ float wave_max64(float m) {
#pragma unroll
  for (int o = 32; o > 0; o >>= 1) m = fmaxf(m, __shfl_xor(m, o));
  return m;
}

__global__ void zero_slots(unsigned* s) {
  if (threadIdx.x < 16) s[threadIdx.x] = 0u;
}

__device__ __forceinline__ void absmax_body(const float* __restrict__ p, int n4,
                                            unsigned* __restrict__ slot) {
  float m = 0.f;
  const int stride = gridDim.x * blockDim.x;
  for (int i = blockIdx.x * blockDim.x + threadIdx.x; i < n4; i += stride) {
    float4 v = reinterpret_cast<const float4*>(p)[i];
    m = fmaxf(fmaxf(fabsf(v.x), fabsf(v.y)), fmaxf(fmaxf(fabsf(v.z), fabsf(v.w)), m));
  }
  m = wave_max64(m);
  __shared__ float wm[4];
  const int lane = threadIdx.x & 63, w = threadIdx.x >> 6;
  if (lane == 0) wm[w] = m;
  __syncthreads();
  if (threadIdx.x == 0) {
    m = fmaxf(fmaxf(wm[0], wm[1]), fmaxf(wm[2], wm[3]));
    atomicMax(slot, __float_as_uint(m));
  }
}

// 4 tensors in one launch: blockIdx.y picks the tensor
__global__ void absmax4(const float* x, const float* w1, const float* w3, const float* w2,
                        unsigned* slots, int n4x, int n4w) {
  const int seg = blockIdx.y;
  const float* p = (seg == 0) ? x : (seg == 1) ? w1 : (seg == 2) ? w3 : w2;
  absmax_body(p, seg == 0 ? n4x : n4w, slots + seg);
}

__device__ __forceinline__ void quant_body(const float* __restrict__ in,
                                           unsigned* __restrict__ out, int n4,
                                           const unsigned* __restrict__ slot) {
  const float s = fmaxf(__uint_as_float(*slot), 1e-8f) / 127.0f;
  const int stride = gridDim.x * blockDim.x;
  for (int i = blockIdx.x * blockDim.x + threadIdx.x; i < n4; i += stride) {
    float4 v = reinterpret_cast<const float4*>(in)[i];
    const int q0 = (int)rintf(v.x / s), q1 = (int)rintf(v.y / s);
    const int q2 = (int)rintf(v.z / s), q3 = (int)rintf(v.w / s);
    out[i] = (unsigned)(q0 & 255) | ((unsigned)(q1 & 255) << 8) |
             ((unsigned)(q2 & 255) << 16) | ((unsigned)(q3 & 255) << 24);
  }
}

__global__ void quant4(const float* x, const float* w1, const float* w3, const float* w2,
                       unsigned* qx, unsigned* qw1, unsigned* qw3, unsigned* qw2,
                       const unsigned* slots, int n4x, int n4w) {
  const int seg = blockIdx.y;
  const float* p = (seg == 0) ? x : (seg == 1) ? w1 : (seg == 2) ? w3 : w2;
  unsigned* o = (seg == 0) ? qx : (seg == 1) ? qw1 : (seg == 2) ? qw3 : qw2;
  quant_body(p, o, seg == 0 ? n4x : n4w, slots + seg);
}

__global__ void quant_kernel(const float* __restrict__ in, unsigned* __restrict__ out,
                             int n4, const unsigned* __restrict__ slot) {
  quant_body(in, out, n4, slot);
}

// ---------------- fused gate+up GLU GEMM: wave-private B, counted vmcnt
// H[M][F] = (A.B1^T*s1)*silu(A.B3^T*s3); A[128-tile][K], B3/B1[F][K] i8.
// Tile 128x256, 8 waves as 1M x 8N: wave w owns output cols w*32..w*32+31,
// hence owns B3/B1 rows w*32..+31 EXCLUSIVELY -> B staging is per-wave
// (wave stages its own 4 KB chunk per tensor) and needs NO barrier, only the
// wave's own vmcnt. Only A (16 KB, 2 coop loads) needs block-wide sync.
// BK=128. LDS = 2 bufs x 81920 {A[128][128] @0, B3 8x[32][128] chunks
// @16384, B1 chunks @49152} = 160 KiB.
// Per tile: vmcnt(8) [drain A(kt)'s 2 oldest; B(kt)'s 8 stay IN FLIGHT
// across the barrier]; SBAR; stage kt+1 (A 2 + B-own 8); read a-frags;
// vmcnt(10) [drain own B(kt), keep kt+1's 10]; read own-chunk b-frags;
// 64 MFMA. Loads never drain to 0 in steady state (T4).
// Swizzle invariant: phys granule = logical ^ (row&7), pre-swizzled global
// source + swizzled ds_read, linear LDS dest (both-sides rule).
__global__ __launch_bounds__(512, 2) void gemm_glu(
    const signed char* __restrict__ Aq, const signed char* __restrict__ B3q,
    const signed char* __restrict__ B1q, float* __restrict__ H,
    const unsigned* __restrict__ slots, unsigned* __restrict__ hslot) {
  constexpr int K = DDIM;
  __shared__ char lds[163840];  // 2 x 81920

  const int t = threadIdx.x;
  const int l = t & 63;
  const int w = t >> 6;  // wave 0..7 = N-column owner

  // XCD-aware column-major chunking (nwg = 43*32 = 1376, %8==0)
  const int gx = gridDim.x, gy = gridDim.y;
  const int nwg = gx * gy;
  const int i0 = blockIdx.y * gx + blockIdx.x;
  const int cid = (i0 & 7) * (nwg >> 3) + (i0 >> 3);
  const int rowA0 = (cid % gy) << 7;  // 128-row tile
  const int colB0 = (cid / gy) << 8;  // 256-col tile

  // A staging (cooperative, 2 lines x 512 thr x 16B): row t>>3, granule
  // pre-swizzled by row&7
  const int rlA = t >> 3;  // 0..63 (+64 for line 1; row&7 invariant)
  const int glA = (t & 7) ^ (rlA & 7);
  const signed char* aP = Aq + (size_t)(rowA0 + rlA) * K + glA * 16;
  const size_t r64 = (size_t)64 * K;
  const int stW = w * 1024;

  // B staging (wave-private, 4 lines/tensor x 64 lanes x 16B):
  // lane l -> local row l>>3 (+8 per line), granule (l&7)^(l>>3)
  const int rlB = l >> 3;  // 0..7
  const int glB = (l & 7) ^ rlB;
  const signed char* b3P = B3q + (size_t)(colB0 + w * 32 + rlB) * K + glB * 16;
  const signed char* b1P = B1q + (size_t)(colB0 + w * 32 + rlB) * K + glB * 16;
  const size_t r8 = (size_t)8 * K;
  const int bBase3 = 16384 + w * 4096;  // within-buffer chunk bases
  const int bBase1 = 49152 + w * 4096;

#define STAGE_A(KO, BUF)                            \
  do {                                              \
    GLDS16(aP + (KO), &lds[(BUF) + stW]);           \
    GLDS16(aP + r64 + (KO), &lds[(BUF) + 8192 + stW]); \
  } while (0)

#define STAGE_B(KO, BUF)                                           \
  do {                                                             \
    GLDS16(b3P + (KO), &lds[(BUF) + bBase3]);                      \
    GLDS16(b3P + r8 + (KO), &lds[(BUF) + bBase3 + 1024]);          \
    GLDS16(b3P + 2 * r8 + (KO), &lds[(BUF) + bBase3 + 2048]);      \
    GLDS16(b3P + 3 * r8 + (KO), &lds[(BUF) + bBase3 + 3072]);      \
    GLDS16(b1P + (KO), &lds[(BUF) + bBase1]);                      \
    GLDS16(b1P + r8 + (KO), &lds[(BUF) + bBase1 + 1024]);          \
    GLDS16(b1P + 2 * r8 + (KO), &lds[(BUF) + bBase1 + 2048]);      \
    GLDS16(b1P + 3 * r8 + (KO), &lds[(BUF) + bBase1 + 3072]);      \
  } while (0)

// swizzled frag read: BASE = region byte base, R = local row, G = granule
#define LDSF(BASE, R, G)                                                      \
  (*reinterpret_cast<const int4v*>(                                           \
      &lds[(BASE) + (R)*128 + (((G) ^ ((R)&7)) << 4)]))

  int4v acc3[8][2], acc1[8][2];
#pragma unroll
  for (int m = 0; m < 8; ++m)
#pragma unroll
    for (int n = 0; n < 2; ++n) {
      acc3[m][n] = (int4v){0, 0, 0, 0};
      acc1[m][n] = (int4v){0, 0, 0, 0};
    }

  const int NT = K >> 7;  // 32
  const int lr = l & 15;
  const int cr = l >> 4;  // granule base (kk adds 4)

  // prologue: tile 0 -> buf 0 (A then B; 10 outstanding)
  STAGE_A(0, 0);
  STAGE_B(0, 0);

  for (int kt = 0; kt < NT; ++kt) {
    const int rb = (kt & 1) * 81920;
    const bool haveNext = (kt + 1 < NT);

    // ---- boundary: drain only A(kt); B(kt)'s 8 stay in flight
    SCHED0();
    asm volatile("s_waitcnt vmcnt(8)" ::: "memory");
    SBAR();  // all waves' A(kt) landed
    SCHED0();

    if (haveNext) {
      const size_t kO = (size_t)(kt + 1) * 128;
      STAGE_A(kO, rb ^ 81920);
      STAGE_B(kO, rb ^ 81920);
    }

    // kk=0 A-frags (A region valid after barrier)
    int4v a[8];
#pragma unroll
    for (int m = 0; m < 8; ++m) a[m] = LDSF(rb, m * 16 + lr, cr);

    // drain own B(kt); keep tile kt+1's 10 in flight
    if (haveNext) {
      asm volatile("s_waitcnt vmcnt(10)" ::: "memory");
    } else {
      asm volatile("s_waitcnt vmcnt(0)" ::: "memory");
    }
    SCHED0();

    int4v b3f[2][2], b1f[2][2];
#pragma unroll
    for (int n = 0; n < 2; ++n) {
      const int R = n * 16 + lr;
      b3f[0][n] = LDSF(rb + bBase3, R, cr);
      b3f[1][n] = LDSF(rb + bBase3, R, 4 + cr);
      b1f[0][n] = LDSF(rb + bBase1, R, cr);
      b1f[1][n] = LDSF(rb + bBase1, R, 4 + cr);
    }

    __builtin_amdgcn_s_setprio(1);
#pragma unroll
    for (int m = 0; m < 8; ++m)
#pragma unroll
      for (int n = 0; n < 2; ++n) {
        acc3[m][n] = MFMA_I8(a[m], b3f[0][n], acc3[m][n]);
        acc1[m][n] = MFMA_I8(a[m], b1f[0][n], acc1[m][n]);
      }
    __builtin_amdgcn_s_setprio(0);

    // kk=1 A-frags + MFMA
#pragma unroll
    for (int m = 0; m < 8; ++m) a[m] = LDSF(rb, m * 16 + lr, 4 + cr);
    __builtin_amdgcn_s_setprio(1);
#pragma unroll
    for (int m = 0; m < 8; ++m)
#pragma unroll
      for (int n = 0; n < 2; ++n) {
        acc3[m][n] = MFMA_I8(a[m], b3f[1][n], acc3[m][n]);
        acc1[m][n] = MFMA_I8(a[m], b1f[1][n], acc1[m][n]);
      }
    __builtin_amdgcn_s_setprio(0);
  }

  // ------------------------------------------------------------- epilogue
  const float sx = fmaxf(__uint_as_float(slots[0]), 1e-8f) / 127.0f;
  const float sw1 = fmaxf(__uint_as_float(slots[1]), 1e-8f) / 127.0f;
  const float sw3 = fmaxf(__uint_as_float(slots[2]), 1e-8f) / 127.0f;
  const float s3 = sx * sw3, s1 = sx * sw1;
  const int crow0 = rowA0 + ((l >> 4) << 2);
  const int ccol0 = colB0 + w * 32 + lr;
  float hmax = 0.f;
#pragma unroll
  for (int m = 0; m < 8; ++m)
#pragma unroll
    for (int n = 0; n < 2; ++n)
#pragma unroll
      for (int j = 0; j < 4; ++j) {
        const int row = crow0 + m * 16 + j;
        const int col = ccol0 + n * 16;
        const float g = (float)acc3[m][n][j] * s3;
        const float gate = g / (1.f + expf(-g));  // silu
        const float h = (float)acc1[m][n][j] * s1 * gate;
        H[(size_t)row * FDIM + col] = h;
        hmax = fmaxf(hmax, fabsf(h));
      }
  hmax = wave_max64(hmax);
  if (l == 0) atomicMax(hslot, __float_as_uint(hmax));
#undef STAGE_A
#undef STAGE_B
#undef LDSF
}

// ------------------------------- 256x256 down GEMM, BK=128, 1 barrier/tile
// out[M][N] = s * A[M][K].B[N][K]^T.  8 waves (2M x 4N), per-wave 128x64
// (acc = 128 VGPR). LDS = 2 bufs x 65536 {A[256][128] @0, B[256][128]
// @32768}. R8 measured-best structure, unchanged.
__global__ __launch_bounds__(512, 2) void gemm_down(
    const signed char* __restrict__ Aq, const signed char* __restrict__ Bq,
    float* __restrict__ C, const unsigned* __restrict__ slots, int sA, int sB,
    int K, int ldc) {
  __shared__ char lds[131072];  // 2 x 65536

  const int t = threadIdx.x;
  const int l = t & 63;
  const int w = t >> 6;
  const int wm = w >> 2;  // 0..1
  const int wn = w & 3;   // 0..3

  const int gx = gridDim.x, gy = gridDim.y;
  const int nwg = gx * gy;
  const int i0 = blockIdx.y * gx + blockIdx.x;
  const int cid = (i0 & 7) * (nwg >> 3) + (i0 >> 3);
  const int rowA0 = (cid % gy) << 8;
  const int colB0 = (cid / gy) << 8;

  const int rl = t >> 3;
  const int gl = (t & 7) ^ (rl & 7);
  const signed char* aP = Aq + (size_t)(rowA0 + rl) * K + gl * 16;
  const signed char* bP = Bq + (size_t)(colB0 + rl) * K + gl * 16;
  const size_t r64 = (size_t)64 * K;
  const int stW = w * 1024;

#define STAGE8(KO, BASE)                                             \
  do {                                                               \
    GLDS16(aP + (KO), &lds[(BASE) + stW]);                           \
    GLDS16(aP + r64 + (KO), &lds[(BASE) + 8192 + stW]);              \
    GLDS16(aP + 2 * r64 + (KO), &lds[(BASE) + 16384 + stW]);         \
    GLDS16(aP + 3 * r64 + (KO), &lds[(BASE) + 24576 + stW]);         \
    GLDS16(bP + (KO), &lds[(BASE) + 32768 + stW]);                   \
    GLDS16(bP + r64 + (KO), &lds[(BASE) + 40960 + stW]);             \
    GLDS16(bP + 2 * r64 + (KO), &lds[(BASE) + 49152 + stW]);         \
    GLDS16(bP + 3 * r64 + (KO), &lds[(BASE) + 57344 + stW]);         \
  } while (0)

#define LDSF(BASE, ROW, G)                                                    \
  (*reinterpret_cast<const int4v*>(                                           \
      &lds[(BASE) + (ROW)*128 + (((G) ^ ((ROW)&7)) << 4)]))

  int4v acc[8][4];
#pragma unroll
  for (int m = 0; m < 8; ++m)
#pragma unroll
    for (int n = 0; n < 4; ++n) acc[m][n] = (int4v){0, 0, 0, 0};

  const int NT = K >> 7;  // 86
  const int arow = wm * 128 + (l & 15);
  const int brow = wn * 64 + (l & 15);
  const int cr = l >> 4;

  STAGE8(0, 0);

  for (int kt = 0; kt < NT; ++kt) {
    const int rb = (kt & 1) * 65536;
    SCHED0();
    asm volatile("s_waitcnt vmcnt(0)" ::: "memory");
    SBAR();
    SCHED0();

    if (kt + 1 < NT) STAGE8((size_t)(kt + 1) * 128, rb ^ 65536);

#pragma unroll
    for (int kk = 0; kk < 2; ++kk) {
      int4v a[8], b[4];
#pragma unroll
      for (int m = 0; m < 8; ++m) a[m] = LDSF(rb, arow + m * 16, kk * 4 + cr);
#pragma unroll
      for (int n = 0; n < 4; ++n) b[n] = LDSF(rb + 32768, brow + n * 16, kk * 4 + cr);
      __builtin_amdgcn_s_setprio(1);
#pragma unroll
      for (int m = 0; m < 8; ++m)
#pragma unroll
        for (int n = 0; n < 4; ++n) acc[m][n] = MFMA_I8(a[m], b[n], acc[m][n]);
      __builtin_amdgcn_s_setprio(0);
    }
  }

  const float sa = fmaxf(__uint_as_float(slots[sA]), 1e-8f) / 127.0f;
  const float sb2 = fmaxf(__uint_as_float(slots[sB]), 1e-8f) / 127.0f;
  const float s = sa * sb2;
  const int crow0 = rowA0 + wm * 128 + ((l >> 4) << 2);
  const int ccol0 = colB0 + wn * 64 + (l & 15);
#pragma unroll
  for (int m = 0; m < 8; ++m)
#pragma unroll
    for (int n = 0; n < 4; ++n)
#pragma unroll
      for (int j = 0; j < 4; ++j) {
        const int row = crow0 + m * 16 + j;
        const int col = ccol0 + n * 16;
        C[(size_t)row * ldc + col] = (float)acc[m][n][j] * s;
      }
#undef STAGE8
#undef LDSF
}

// ------------------------------------------------------------------- launch

extern "C" void kernel_launch(void* const* d_in, const int* in_sizes, int n_in,
                              void* d_out, int out_size, void* d_ws, size_t ws_size,
                              hipStream_t stream) {
  const float* x = (const float*)d_in[0];
  const float* w1 = (const float*)d_in[1];
  const float* w3 = (const float*)d_in[2];
  const float* w2 = (const float*)d_in[3];
  float* out = (float*)d_out;
  char* ws = (char*)d_ws;

  unsigned* slots = (unsigned*)ws;  // [0]=x [1]=w1 [2]=w3 [3]=w2 [4]=h absmax
  size_t off = 256;
  signed char* qx = (signed char*)(ws + off);
  off += (size_t)NTOK * DDIM;
  signed char* qw3 = (signed char*)(ws + off);
  off += (size_t)FDIM * DDIM;
  signed char* qw1 = (signed char*)(ws + off);
  off += (size_t)FDIM * DDIM;
  signed char* qw2 = (signed char*)(ws + off);
  off += (size_t)FDIM * DDIM;
  float* H = (float*)(ws + off);
  off += (size_t)NTOK * FDIM * 4;
  signed char* qh = (signed char*)(ws + off);
  off += (size_t)NTOK * FDIM;  // ~385 MB total

  const int n4x = NTOK * DDIM / 4;
  const int n4w = FDIM * DDIM / 4;
  const int n4h = NTOK * FDIM / 4;

  zero_slots<<<1, 64, 0, stream>>>(slots);
  absmax4<<<dim3(512, 4), 256, 0, stream>>>(x, w1, w3, w2, slots, n4x, n4w);
  quant4<<<dim3(512, 4), 256, 0, stream>>>(x, w1, w3, w2, (unsigned*)qx, (unsigned*)qw1,
                                           (unsigned*)qw3, (unsigned*)qw2, slots, n4x, n4w);

  // fused gate+up: H = (x.w1^T*s1) * silu(x.w3^T*s3), + absmax(H)
  const dim3 gGlu(FDIM / 256, NTOK / 128);  // 43 x 32 = 1376 wgs
  gemm_glu<<<gGlu, 512, 0, stream>>>(qx, qw3, qw1, H, slots, slots + 4);
  quant_kernel<<<2048, 256, 0, stream>>>(H, (unsigned*)qh, n4h, slots + 4);
  // down: out = (h.w2^T) * s
  const dim3 gDn(DDIM / 256, NTOK / 256);  // 16 x 16 = 256 wgs
  gemm_down<<<gDn, 512, 0, stream>>>(qh, qw2, out, slots, 4, 3, FDIM, DDIM);
}